// Round 1
// baseline (629.686 us; speedup 1.0000x reference)
//
#include <hip/hip_runtime.h>
#include <hip/hip_bf16.h>
#include <math.h>

#define NN 50000
#define EE 800000
#define F_IN 16
#define HID 32
#define HEADS 4
#define HC 128
#define NCLS 5
#define EF 8
#define NEG_SLOPE 0.2f
#define SCAN_BLOCKS 196  // ceil(50000/256)

typedef __attribute__((ext_vector_type(8))) short short8;
typedef __attribute__((ext_vector_type(4))) float floatx4;

__device__ __forceinline__ float lrelu_f(float v) { return v > 0.f ? v : NEG_SLOPE * v; }
__device__ __forceinline__ float elu_f(float v) { return v > 0.f ? v : expm1f(v); }
__device__ __forceinline__ unsigned short f2bf(float v) {
  __hip_bfloat16 b = __float2bfloat16(v);
  unsigned short u; __builtin_memcpy(&u, &b, 2); return u;
}

// ve[layer*16 + k*4 + h] = sum_c We[(h*32+c)*4 + k] * ae[h*32+c]
__global__ void k_prep_ve(const float* __restrict__ We1, const float* __restrict__ ae1,
                          const float* __restrict__ We2, const float* __restrict__ ae2,
                          float* __restrict__ ve) {
  int t = threadIdx.x;
  if (t >= 32) return;
  int layer = t >> 4, idx = t & 15, k = idx >> 2, h = idx & 3;
  const float* We = layer ? We2 : We1;
  const float* ae = layer ? ae2 : ae1;
  float s = 0.f;
  for (int c = 0; c < HID; ++c) s += We[(h*HID + c)*HEADS + k] * ae[h*HID + c];
  ve[layer*16 + k*4 + h] = s;
}

// edge encoder: ea = relu(attr@w1^T+b1)@w2^T+b2 ; a_e_l = ea @ ve_l  -> float4 per edge per layer
__global__ void __launch_bounds__(256) k_edge_enc(
    const float* __restrict__ eattr, const float* __restrict__ w1, const float* __restrict__ b1,
    const float* __restrict__ w2, const float* __restrict__ b2, const float* __restrict__ ve,
    float4* __restrict__ a_e1, float4* __restrict__ a_e2) {
  __shared__ float sw1[HID*EF], sb1[HID], sw2[HEADS*HID], sb2[HEADS], sve[32];
  int tid = threadIdx.x;
  sw1[tid] = w1[tid];                       // 256 elements exactly
  if (tid < HID) sb1[tid] = b1[tid];
  if (tid < HEADS*HID) sw2[tid] = w2[tid];
  if (tid < HEADS) sb2[tid] = b2[tid];
  if (tid < 32) sve[tid] = ve[tid];
  __syncthreads();
  int e = blockIdx.x*256 + tid;
  if (e >= EE) return;
  const float4* ap = (const float4*)(eattr + (size_t)e*EF);
  float4 A0 = ap[0], A1 = ap[1];
  float ea0=A0.x, ea1=A0.y, ea2=A0.z, ea3=A0.w, ea4=A1.x, ea5=A1.y, ea6=A1.z, ea7=A1.w;
  float enc0=sb2[0], enc1=sb2[1], enc2=sb2[2], enc3=sb2[3];
  #pragma unroll
  for (int j = 0; j < HID; ++j) {
    float hsum = sb1[j];
    hsum = fmaf(ea0, sw1[j*EF+0], hsum); hsum = fmaf(ea1, sw1[j*EF+1], hsum);
    hsum = fmaf(ea2, sw1[j*EF+2], hsum); hsum = fmaf(ea3, sw1[j*EF+3], hsum);
    hsum = fmaf(ea4, sw1[j*EF+4], hsum); hsum = fmaf(ea5, sw1[j*EF+5], hsum);
    hsum = fmaf(ea6, sw1[j*EF+6], hsum); hsum = fmaf(ea7, sw1[j*EF+7], hsum);
    hsum = fmaxf(hsum, 0.f);
    enc0 = fmaf(hsum, sw2[0*HID+j], enc0);
    enc1 = fmaf(hsum, sw2[1*HID+j], enc1);
    enc2 = fmaf(hsum, sw2[2*HID+j], enc2);
    enc3 = fmaf(hsum, sw2[3*HID+j], enc3);
  }
  float4 r1, r2;
  r1.x = enc0*sve[0]  + enc1*sve[4]  + enc2*sve[8]   + enc3*sve[12];
  r1.y = enc0*sve[1]  + enc1*sve[5]  + enc2*sve[9]   + enc3*sve[13];
  r1.z = enc0*sve[2]  + enc1*sve[6]  + enc2*sve[10]  + enc3*sve[14];
  r1.w = enc0*sve[3]  + enc1*sve[7]  + enc2*sve[11]  + enc3*sve[15];
  r2.x = enc0*sve[16] + enc1*sve[20] + enc2*sve[24]  + enc3*sve[28];
  r2.y = enc0*sve[17] + enc1*sve[21] + enc2*sve[25]  + enc3*sve[29];
  r2.z = enc0*sve[18] + enc1*sve[22] + enc2*sve[26]  + enc3*sve[30];
  r2.w = enc0*sve[19] + enc1*sve[23] + enc2*sve[27]  + enc3*sve[31];
  a_e1[e] = r1; a_e2[e] = r2;
}

__global__ void __launch_bounds__(256) k_hist(const int* __restrict__ ei, int* __restrict__ counts) {
  int e = blockIdx.x*256 + threadIdx.x;
  if (e >= EE) return;
  atomicAdd(&counts[ei[EE + e]], 1);
}

__global__ void __launch_bounds__(256) k_scan_block(const int* __restrict__ counts, int* __restrict__ bsum) {
  __shared__ int s[256];
  int tid = threadIdx.x;
  int idx = blockIdx.x*256 + tid;
  s[tid] = (idx < NN) ? counts[idx] : 0;
  for (int o = 128; o; o >>= 1) { __syncthreads(); if (tid < o) s[tid] += s[tid + o]; }
  if (tid == 0) bsum[blockIdx.x] = s[0];
}

__global__ void __launch_bounds__(256) k_scan_top(const int* __restrict__ bsum, int* __restrict__ bexcl,
                                                  int* __restrict__ row_start) {
  __shared__ int s[256];
  int tid = threadIdx.x;
  int v = (tid < SCAN_BLOCKS) ? bsum[tid] : 0;
  s[tid] = v; __syncthreads();
  for (int o = 1; o < 256; o <<= 1) {
    int t2 = (tid >= o) ? s[tid - o] : 0;
    __syncthreads();
    s[tid] += t2;
    __syncthreads();
  }
  if (tid < SCAN_BLOCKS) bexcl[tid] = s[tid] - v;
  if (tid == 0) row_start[NN] = EE;
}

__global__ void __launch_bounds__(256) k_scan_final(const int* __restrict__ counts, const int* __restrict__ bexcl,
                                                    int* __restrict__ row_start, int* __restrict__ cursor) {
  __shared__ int s[256];
  int tid = threadIdx.x;
  int idx = blockIdx.x*256 + tid;
  int v = (idx < NN) ? counts[idx] : 0;
  s[tid] = v; __syncthreads();
  for (int o = 1; o < 256; o <<= 1) {
    int t2 = (tid >= o) ? s[tid - o] : 0;
    __syncthreads();
    s[tid] += t2;
    __syncthreads();
  }
  int excl = s[tid] - v + bexcl[blockIdx.x];
  if (idx < NN) { row_start[idx] = excl; cursor[idx] = excl; }
}

__global__ void __launch_bounds__(256) k_scatter(const int* __restrict__ ei, int* __restrict__ cursor,
                                                 int2* __restrict__ adj) {
  int e = blockIdx.x*256 + threadIdx.x;
  if (e >= EE) return;
  int src = ei[e], dst = ei[EE + e];
  int pos = atomicAdd(&cursor[dst], 1);
  adj[pos] = make_int2(src, e);
}

// layer-1 node phase: xp = x @ W^T (per-channel), a_src/a_dst per (node,head)
__global__ void __launch_bounds__(128) k_node1(const float* __restrict__ x, const float* __restrict__ W,
                                               const float* __restrict__ as_, const float* __restrict__ ad_,
                                               float* __restrict__ xp, float* __restrict__ a_src,
                                               float* __restrict__ a_dst) {
  __shared__ float sW[HC*17];            // pad 17: conflict-free ds reads
  __shared__ float sas[HC], sad[HC];
  __shared__ float sx[F_IN];
  int tid = threadIdx.x;
  for (int i = tid; i < HC*F_IN; i += 128) { int r = i >> 4, k = i & 15; sW[r*17 + k] = W[i]; }
  sas[tid] = as_[tid]; sad[tid] = ad_[tid];
  int h = tid >> 5;
  for (int n = blockIdx.x; n < NN; n += gridDim.x) {
    __syncthreads();
    if (tid < F_IN) sx[tid] = x[(size_t)n*F_IN + tid];
    __syncthreads();
    float xv = 0.f;
    #pragma unroll
    for (int k = 0; k < F_IN; ++k) xv = fmaf(sx[k], sW[tid*17 + k], xv);
    xp[(size_t)n*HC + tid] = xv;
    float vs = xv * sas[tid], vd = xv * sad[tid];
    #pragma unroll
    for (int m = 16; m; m >>= 1) { vs += __shfl_xor(vs, m); vd += __shfl_xor(vd, m); }
    if ((tid & 31) == 0) { a_src[n*HEADS + h] = vs; a_dst[n*HEADS + h] = vd; }
  }
}

// fused layer-1: scores + online softmax-sum + aggregate + bias + elu -> h1 (bf16)
__global__ void __launch_bounds__(128) k_agg1(const int* __restrict__ row_start, const int2* __restrict__ adj,
                                              const float* __restrict__ xp, const float* __restrict__ a_src,
                                              const float* __restrict__ a_dst, const float* __restrict__ a_e,
                                              const float* __restrict__ bias, unsigned short* __restrict__ h1b) {
  int n = blockIdx.x;
  int c = threadIdx.x, h = c >> 5;
  int beg = row_start[n], end = row_start[n + 1];
  float adh = a_dst[n*HEADS + h];
  float acc = 0.f, ssum = 0.f;
  for (int i = beg; i < end; ++i) {
    int2 se = adj[i];
    float v = a_src[se.x*HEADS + h] + adh + a_e[(size_t)se.y*HEADS + h];
    v = lrelu_f(v);
    float ev = __expf(v);
    ssum += ev;
    acc = fmaf(ev, xp[(size_t)se.x*HC + c], acc);
  }
  float val = elu_f(acc / (ssum + 1e-16f) + bias[c]);
  h1b[(size_t)n*HC + c] = f2bf(val);
}

__global__ void __launch_bounds__(256) k_tobf16(const float* __restrict__ in, unsigned short* __restrict__ out, int n) {
  int i = blockIdx.x*256 + threadIdx.x;
  if (i < n) out[i] = f2bf(in[i]);
}

// layer-2 node GEMM: xp2[m, n] = sum_k h1b[m,k] * w2b[n,k]  via 16x16x32 bf16 MFMA
__global__ void __launch_bounds__(256) k_xp2(const unsigned short* __restrict__ h1b,
                                             const unsigned short* __restrict__ w2b,
                                             float* __restrict__ xp) {
  int wave = threadIdx.x >> 6;
  int lane = threadIdx.x & 63;
  int m0 = (blockIdx.x*4 + wave)*16;
  if (m0 >= NN) return;
  int ln = lane & 15;     // A: m within tile | B: n within tile | D: col (n)
  int quad = lane >> 4;   // k sub-chunk / D row group
  const short8* arow = (const short8*)(h1b + (size_t)(m0 + ln)*HC) + quad;
  short8 a[4];
  #pragma unroll
  for (int kc = 0; kc < 4; ++kc) a[kc] = arow[kc*4];
  #pragma unroll
  for (int n0 = 0; n0 < 8; ++n0) {
    const short8* brow = (const short8*)(w2b + (size_t)(n0*16 + ln)*HC) + quad;
    floatx4 acc = {0.f, 0.f, 0.f, 0.f};
    #pragma unroll
    for (int kc = 0; kc < 4; ++kc) {
      short8 b = brow[kc*4];
      acc = __builtin_amdgcn_mfma_f32_16x16x32_bf16(a[kc], b, acc, 0, 0, 0);
    }
    #pragma unroll
    for (int r = 0; r < 4; ++r) {
      int mm = quad*4 + r;
      xp[(size_t)(m0 + mm)*HC + n0*16 + ln] = acc[r];
    }
  }
}

// layer-2 attention coefficients from xp2
__global__ void __launch_bounds__(256) k_coef2(const float* __restrict__ xp, const float* __restrict__ as_,
                                               const float* __restrict__ ad_, float* __restrict__ a_src,
                                               float* __restrict__ a_dst) {
  int t = blockIdx.x*256 + threadIdx.x;
  if (t >= NN*HEADS) return;
  int n = t >> 2, h = t & 3;
  const float* base = xp + (size_t)n*HC + h*HID;
  float s = 0.f, d = 0.f;
  #pragma unroll
  for (int j = 0; j < HID; ++j) {
    float v = base[j];
    s = fmaf(v, as_[h*HID + j], s);
    d = fmaf(v, ad_[h*HID + j], d);
  }
  a_src[t] = s; a_dst[t] = d;
}

// fused layer-2 + skip + classifier
__global__ void __launch_bounds__(128) k_final(const int* __restrict__ row_start, const int2* __restrict__ adj,
                                               const float* __restrict__ xp, const float* __restrict__ a_src,
                                               const float* __restrict__ a_dst, const float* __restrict__ a_e,
                                               const float* __restrict__ g2b, const float* __restrict__ x,
                                               const float* __restrict__ skw, const float* __restrict__ skb,
                                               const float* __restrict__ clw, const float* __restrict__ clb,
                                               float* __restrict__ out) {
  __shared__ float sh[HC];
  __shared__ float sx[F_IN];
  int n = blockIdx.x;
  int c = threadIdx.x, h = c >> 5;
  if (c < F_IN) sx[c] = x[(size_t)n*F_IN + c];
  int beg = row_start[n], end = row_start[n + 1];
  float adh = a_dst[n*HEADS + h];
  float acc = 0.f, ssum = 0.f;
  for (int i = beg; i < end; ++i) {
    int2 se = adj[i];
    float v = a_src[se.x*HEADS + h] + adh + a_e[(size_t)se.y*HEADS + h];
    v = lrelu_f(v);
    float ev = __expf(v);
    ssum += ev;
    acc = fmaf(ev, xp[(size_t)se.x*HC + c], acc);
  }
  float val = elu_f(acc / (ssum + 1e-16f) + g2b[c]);
  float skipv = skb[c];
  __syncthreads();
  #pragma unroll
  for (int k = 0; k < F_IN; ++k) skipv = fmaf(sx[k], skw[c*F_IN + k], skipv);
  sh[c] = val + skipv;
  __syncthreads();
  if (c < NCLS) {
    float o = clb[c];
    #pragma unroll 8
    for (int k = 0; k < HC; ++k) o = fmaf(sh[k], clw[c*HC + k], o);
    out[(size_t)n*NCLS + c] = o;
  }
}

extern "C" void kernel_launch(void* const* d_in, const int* in_sizes, int n_in,
                              void* d_out, int out_size, void* d_ws, size_t ws_size,
                              hipStream_t stream) {
  const float* x      = (const float*)d_in[0];
  const int*   ei     = (const int*)d_in[1];
  const float* eattr  = (const float*)d_in[2];
  const float* ee_w1  = (const float*)d_in[3];
  const float* ee_b1  = (const float*)d_in[4];
  const float* ee_w2  = (const float*)d_in[5];
  const float* ee_b2  = (const float*)d_in[6];
  const float* g1_W   = (const float*)d_in[7];
  const float* g1_We  = (const float*)d_in[8];
  const float* g1_as  = (const float*)d_in[9];
  const float* g1_ad  = (const float*)d_in[10];
  const float* g1_ae  = (const float*)d_in[11];
  const float* g1_b   = (const float*)d_in[12];
  const float* g2_W   = (const float*)d_in[13];
  const float* g2_We  = (const float*)d_in[14];
  const float* g2_as  = (const float*)d_in[15];
  const float* g2_ad  = (const float*)d_in[16];
  const float* g2_ae  = (const float*)d_in[17];
  const float* g2_b   = (const float*)d_in[18];
  const float* skip_w = (const float*)d_in[19];
  const float* skip_b = (const float*)d_in[20];
  const float* cls_w  = (const float*)d_in[21];
  const float* cls_b  = (const float*)d_in[22];
  float* out = (float*)d_out;
  (void)in_sizes; (void)n_in; (void)out_size; (void)ws_size;

  char* ws = (char*)d_ws;
  size_t off = 0;
  auto alloc = [&](size_t bytes) -> void* {
    void* p = ws + off;
    off = (off + bytes + 255) & ~(size_t)255;
    return p;
  };
  float* ve          = (float*)alloc(32*4);
  int* counts        = (int*)alloc((size_t)NN*4);
  int* row_start     = (int*)alloc((size_t)(NN + 1)*4);
  int* cursor        = (int*)alloc((size_t)NN*4);
  int* bexcl         = (int*)alloc(256*4);
  int* bsum          = (int*)alloc(256*4);
  float4* a_e1       = (float4*)alloc((size_t)EE*16);
  float4* a_e2       = (float4*)alloc((size_t)EE*16);
  int2* adj          = (int2*)alloc((size_t)EE*8);
  float* xp          = (float*)alloc((size_t)NN*HC*4);   // reused for layer-2 xp
  unsigned short* h1b = (unsigned short*)alloc((size_t)NN*HC*2);
  unsigned short* w2b = (unsigned short*)alloc((size_t)HC*HC*2);
  float* a_src       = (float*)alloc((size_t)NN*HEADS*4); // reused layer-2
  float* a_dst       = (float*)alloc((size_t)NN*HEADS*4);

  hipMemsetAsync(counts, 0, (size_t)NN*4, stream);
  k_prep_ve<<<1, 32, 0, stream>>>(g1_We, g1_ae, g2_We, g2_ae, ve);
  k_edge_enc<<<EE/256, 256, 0, stream>>>(eattr, ee_w1, ee_b1, ee_w2, ee_b2, ve, a_e1, a_e2);
  k_hist<<<EE/256, 256, 0, stream>>>(ei, counts);
  k_scan_block<<<SCAN_BLOCKS, 256, 0, stream>>>(counts, bsum);
  k_scan_top<<<1, 256, 0, stream>>>(bsum, bexcl, row_start);
  k_scan_final<<<SCAN_BLOCKS, 256, 0, stream>>>(counts, bexcl, row_start, cursor);
  k_scatter<<<EE/256, 256, 0, stream>>>(ei, cursor, adj);
  k_node1<<<2048, 128, 0, stream>>>(x, g1_W, g1_as, g1_ad, xp, a_src, a_dst);
  k_agg1<<<NN, 128, 0, stream>>>(row_start, adj, xp, a_src, a_dst, (const float*)a_e1, g1_b, h1b);
  k_tobf16<<<(HC*HC)/256, 256, 0, stream>>>(g2_W, w2b, HC*HC);
  k_xp2<<<(NN/16 + 3)/4, 256, 0, stream>>>(h1b, w2b, xp);
  k_coef2<<<(NN*HEADS + 255)/256, 256, 0, stream>>>(xp, g2_as, g2_ad, a_src, a_dst);
  k_final<<<NN, 128, 0, stream>>>(row_start, adj, xp, a_src, a_dst, (const float*)a_e2,
                                  g2_b, x, skip_w, skip_b, cls_w, cls_b, out);
}

// Round 2
// 471.521 us; speedup vs baseline: 1.3354x; 1.3354x over previous
//
#include <hip/hip_runtime.h>
#include <hip/hip_bf16.h>
#include <math.h>

#define NN 50000
#define EE 800000
#define F_IN 16
#define HID 32
#define HEADS 4
#define HC 128
#define NCLS 5
#define EF 8
#define NEG_SLOPE 0.2f
#define SCAN_BLOCKS 196  // ceil(50000/256)

typedef __attribute__((ext_vector_type(8))) short short8;
typedef __attribute__((ext_vector_type(4))) float floatx4;

__device__ __forceinline__ float lrelu_f(float v) { return v > 0.f ? v : NEG_SLOPE * v; }
__device__ __forceinline__ float elu_f(float v) { return v > 0.f ? v : expm1f(v); }
__device__ __forceinline__ unsigned short f2bf(float v) {
  __hip_bfloat16 b = __float2bfloat16(v);
  unsigned short u; __builtin_memcpy(&u, &b, 2); return u;
}
__device__ __forceinline__ float bf2f(unsigned short u) {
  unsigned v = (unsigned)u << 16; float f; __builtin_memcpy(&f, &v, 4); return f;
}

// ve[layer*16 + k*4 + h] = sum_c We[(h*32+c)*4 + k] * ae[h*32+c]
__global__ void k_prep_ve(const float* __restrict__ We1, const float* __restrict__ ae1,
                          const float* __restrict__ We2, const float* __restrict__ ae2,
                          float* __restrict__ ve) {
  int t = threadIdx.x;
  if (t >= 32) return;
  int layer = t >> 4, idx = t & 15, k = idx >> 2, h = idx & 3;
  const float* We = layer ? We2 : We1;
  const float* ae = layer ? ae2 : ae1;
  float s = 0.f;
  for (int c = 0; c < HID; ++c) s += We[(h*HID + c)*HEADS + k] * ae[h*HID + c];
  ve[layer*16 + k*4 + h] = s;
}

// edge encoder: ea = relu(attr@w1^T+b1)@w2^T+b2 ; a_e_l = ea @ ve_l -> float4/edge/layer
__global__ void __launch_bounds__(256) k_edge_enc(
    const float* __restrict__ eattr, const float* __restrict__ w1, const float* __restrict__ b1,
    const float* __restrict__ w2, const float* __restrict__ b2, const float* __restrict__ ve,
    float4* __restrict__ a_e1, float4* __restrict__ a_e2) {
  __shared__ float sw1[HID*EF], sb1[HID], sw2[HEADS*HID], sb2[HEADS], sve[32];
  int tid = threadIdx.x;
  sw1[tid] = w1[tid];
  if (tid < HID) sb1[tid] = b1[tid];
  if (tid < HEADS*HID) sw2[tid] = w2[tid];
  if (tid < HEADS) sb2[tid] = b2[tid];
  if (tid < 32) sve[tid] = ve[tid];
  __syncthreads();
  int e = blockIdx.x*256 + tid;
  if (e >= EE) return;
  const float4* ap = (const float4*)(eattr + (size_t)e*EF);
  float4 A0 = ap[0], A1 = ap[1];
  float ea0=A0.x, ea1=A0.y, ea2=A0.z, ea3=A0.w, ea4=A1.x, ea5=A1.y, ea6=A1.z, ea7=A1.w;
  float enc0=sb2[0], enc1=sb2[1], enc2=sb2[2], enc3=sb2[3];
  #pragma unroll
  for (int j = 0; j < HID; ++j) {
    float hsum = sb1[j];
    hsum = fmaf(ea0, sw1[j*EF+0], hsum); hsum = fmaf(ea1, sw1[j*EF+1], hsum);
    hsum = fmaf(ea2, sw1[j*EF+2], hsum); hsum = fmaf(ea3, sw1[j*EF+3], hsum);
    hsum = fmaf(ea4, sw1[j*EF+4], hsum); hsum = fmaf(ea5, sw1[j*EF+5], hsum);
    hsum = fmaf(ea6, sw1[j*EF+6], hsum); hsum = fmaf(ea7, sw1[j*EF+7], hsum);
    hsum = fmaxf(hsum, 0.f);
    enc0 = fmaf(hsum, sw2[0*HID+j], enc0);
    enc1 = fmaf(hsum, sw2[1*HID+j], enc1);
    enc2 = fmaf(hsum, sw2[2*HID+j], enc2);
    enc3 = fmaf(hsum, sw2[3*HID+j], enc3);
  }
  float4 r1, r2;
  r1.x = enc0*sve[0]  + enc1*sve[4]  + enc2*sve[8]   + enc3*sve[12];
  r1.y = enc0*sve[1]  + enc1*sve[5]  + enc2*sve[9]   + enc3*sve[13];
  r1.z = enc0*sve[2]  + enc1*sve[6]  + enc2*sve[10]  + enc3*sve[14];
  r1.w = enc0*sve[3]  + enc1*sve[7]  + enc2*sve[11]  + enc3*sve[15];
  r2.x = enc0*sve[16] + enc1*sve[20] + enc2*sve[24]  + enc3*sve[28];
  r2.y = enc0*sve[17] + enc1*sve[21] + enc2*sve[25]  + enc3*sve[29];
  r2.z = enc0*sve[18] + enc1*sve[22] + enc2*sve[26]  + enc3*sve[30];
  r2.w = enc0*sve[19] + enc1*sve[23] + enc2*sve[27]  + enc3*sve[31];
  a_e1[e] = r1; a_e2[e] = r2;
}

__global__ void __launch_bounds__(256) k_hist(const int* __restrict__ ei, int* __restrict__ counts) {
  int e = blockIdx.x*256 + threadIdx.x;
  if (e >= EE) return;
  atomicAdd(&counts[ei[EE + e]], 1);
}

__global__ void __launch_bounds__(256) k_scan_block(const int* __restrict__ counts, int* __restrict__ bsum) {
  __shared__ int s[256];
  int tid = threadIdx.x;
  int idx = blockIdx.x*256 + tid;
  s[tid] = (idx < NN) ? counts[idx] : 0;
  for (int o = 128; o; o >>= 1) { __syncthreads(); if (tid < o) s[tid] += s[tid + o]; }
  if (tid == 0) bsum[blockIdx.x] = s[0];
}

__global__ void __launch_bounds__(256) k_scan_top(const int* __restrict__ bsum, int* __restrict__ bexcl,
                                                  int* __restrict__ row_start) {
  __shared__ int s[256];
  int tid = threadIdx.x;
  int v = (tid < SCAN_BLOCKS) ? bsum[tid] : 0;
  s[tid] = v; __syncthreads();
  for (int o = 1; o < 256; o <<= 1) {
    int t2 = (tid >= o) ? s[tid - o] : 0;
    __syncthreads();
    s[tid] += t2;
    __syncthreads();
  }
  if (tid < SCAN_BLOCKS) bexcl[tid] = s[tid] - v;
  if (tid == 0) row_start[NN] = EE;
}

__global__ void __launch_bounds__(256) k_scan_final(const int* __restrict__ counts, const int* __restrict__ bexcl,
                                                    int* __restrict__ row_start, int* __restrict__ cursor) {
  __shared__ int s[256];
  int tid = threadIdx.x;
  int idx = blockIdx.x*256 + tid;
  int v = (idx < NN) ? counts[idx] : 0;
  s[tid] = v; __syncthreads();
  for (int o = 1; o < 256; o <<= 1) {
    int t2 = (tid >= o) ? s[tid - o] : 0;
    __syncthreads();
    s[tid] += t2;
    __syncthreads();
  }
  int excl = s[tid] - v + bexcl[blockIdx.x];
  if (idx < NN) { row_start[idx] = excl; cursor[idx] = excl; }
}

__global__ void __launch_bounds__(256) k_scatter(const int* __restrict__ ei, int* __restrict__ cursor,
                                                 int2* __restrict__ adj) {
  int e = blockIdx.x*256 + threadIdx.x;
  if (e >= EE) return;
  int src = ei[e], dst = ei[EE + e];
  int pos = atomicAdd(&cursor[dst], 1);
  adj[pos] = make_int2(src, e);
}

// dstp[pos] = destination node of CSR slot pos
__global__ void __launch_bounds__(256) k_expand_dst(const int* __restrict__ row_start, int* __restrict__ dstp) {
  int n = blockIdx.x*256 + threadIdx.x;
  if (n >= NN) return;
  int b = row_start[n], e = row_start[n + 1];
  for (int i = b; i < e; ++i) dstp[i] = n;
}

// layer-1 node phase: xpb = bf16(x @ W^T), a_src/a_dst per (node,head)
__global__ void __launch_bounds__(128) k_node1(const float* __restrict__ x, const float* __restrict__ W,
                                               const float* __restrict__ as_, const float* __restrict__ ad_,
                                               unsigned short* __restrict__ xpb, float* __restrict__ a_src,
                                               float* __restrict__ a_dst) {
  __shared__ float sW[HC*17];
  __shared__ float sas[HC], sad[HC];
  __shared__ float sx[F_IN];
  int tid = threadIdx.x;
  for (int i = tid; i < HC*F_IN; i += 128) { int r = i >> 4, k = i & 15; sW[r*17 + k] = W[i]; }
  sas[tid] = as_[tid]; sad[tid] = ad_[tid];
  int h = tid >> 5;
  for (int n = blockIdx.x; n < NN; n += gridDim.x) {
    __syncthreads();
    if (tid < F_IN) sx[tid] = x[(size_t)n*F_IN + tid];
    __syncthreads();
    float xv = 0.f;
    #pragma unroll
    for (int k = 0; k < F_IN; ++k) xv = fmaf(sx[k], sW[tid*17 + k], xv);
    xpb[(size_t)n*HC + tid] = f2bf(xv);
    float vs = xv * sas[tid], vd = xv * sad[tid];
    #pragma unroll
    for (int m = 16; m; m >>= 1) { vs += __shfl_xor(vs, m); vd += __shfl_xor(vd, m); }
    if ((tid & 31) == 0) { a_src[n*HEADS + h] = vs; a_dst[n*HEADS + h] = vd; }
  }
}

// per-edge exp weights: ew[pos*4+h] = exp(lrelu(a_src[src]+a_dst[dst]+a_e[eid]))
__global__ void __launch_bounds__(256) k_escore(const int2* __restrict__ adj, const int* __restrict__ dstp,
                                                const float* __restrict__ a_src, const float* __restrict__ a_dst,
                                                const float* __restrict__ a_e, float* __restrict__ ew) {
  int t = blockIdx.x*256 + threadIdx.x;
  if (t >= EE*HEADS) return;
  int pos = t >> 2, h = t & 3;
  int2 se = adj[pos];
  int dst = dstp[pos];
  float v = a_src[se.x*HEADS + h] + a_dst[dst*HEADS + h] + a_e[(size_t)se.y*HEADS + h];
  ew[t] = __expf(lrelu_f(v));
}

// fused layer-1 aggregate: softmax-normalize + bias + elu -> h1 (bf16)
__global__ void __launch_bounds__(128) k_agg1(const int* __restrict__ row_start, const int2* __restrict__ adj,
                                              const unsigned short* __restrict__ xpb, const float* __restrict__ ew,
                                              const float* __restrict__ bias, unsigned short* __restrict__ h1b) {
  int n = blockIdx.x;
  int c = threadIdx.x, h = c >> 5;
  int beg = row_start[n], end = row_start[n + 1];
  float acc = 0.f, ssum = 0.f;
  int i = beg;
  for (; i + 3 < end; i += 4) {
    int s0 = adj[i].x, s1 = adj[i+1].x, s2 = adj[i+2].x, s3 = adj[i+3].x;
    float w0 = ew[(size_t)i*4 + h], w1 = ew[(size_t)(i+1)*4 + h];
    float w2 = ew[(size_t)(i+2)*4 + h], w3 = ew[(size_t)(i+3)*4 + h];
    float x0 = bf2f(xpb[(size_t)s0*HC + c]), x1 = bf2f(xpb[(size_t)s1*HC + c]);
    float x2 = bf2f(xpb[(size_t)s2*HC + c]), x3 = bf2f(xpb[(size_t)s3*HC + c]);
    ssum += (w0 + w1) + (w2 + w3);
    acc = fmaf(w0, x0, fmaf(w1, x1, fmaf(w2, x2, fmaf(w3, x3, acc))));
  }
  for (; i < end; ++i) {
    int s0 = adj[i].x;
    float w0 = ew[(size_t)i*4 + h];
    ssum += w0;
    acc = fmaf(w0, bf2f(xpb[(size_t)s0*HC + c]), acc);
  }
  float val = elu_f(acc / (ssum + 1e-16f) + bias[c]);
  h1b[(size_t)n*HC + c] = f2bf(val);
}

__global__ void __launch_bounds__(256) k_tobf16(const float* __restrict__ in, unsigned short* __restrict__ out, int n) {
  int i = blockIdx.x*256 + threadIdx.x;
  if (i < n) out[i] = f2bf(in[i]);
}

// layer-2 node GEMM: xp2 = h1b @ W2^T via 16x16x32 bf16 MFMA, write bf16
__global__ void __launch_bounds__(256) k_xp2(const unsigned short* __restrict__ h1b,
                                             const unsigned short* __restrict__ w2b,
                                             unsigned short* __restrict__ xpb) {
  int wave = threadIdx.x >> 6;
  int lane = threadIdx.x & 63;
  int m0 = (blockIdx.x*4 + wave)*16;
  if (m0 >= NN) return;
  int ln = lane & 15;
  int quad = lane >> 4;
  const short8* arow = (const short8*)(h1b + (size_t)(m0 + ln)*HC) + quad;
  short8 a[4];
  #pragma unroll
  for (int kc = 0; kc < 4; ++kc) a[kc] = arow[kc*4];
  #pragma unroll
  for (int n0 = 0; n0 < 8; ++n0) {
    const short8* brow = (const short8*)(w2b + (size_t)(n0*16 + ln)*HC) + quad;
    floatx4 acc = {0.f, 0.f, 0.f, 0.f};
    #pragma unroll
    for (int kc = 0; kc < 4; ++kc) {
      short8 b = brow[kc*4];
      acc = __builtin_amdgcn_mfma_f32_16x16x32_bf16(a[kc], b, acc, 0, 0, 0);
    }
    #pragma unroll
    for (int r = 0; r < 4; ++r) {
      int mm = quad*4 + r;
      xpb[(size_t)(m0 + mm)*HC + n0*16 + ln] = f2bf(acc[r]);
    }
  }
}

// layer-2 attention coefficients from bf16 xp2
__global__ void __launch_bounds__(256) k_coef2(const unsigned short* __restrict__ xpb, const float* __restrict__ as_,
                                               const float* __restrict__ ad_, float* __restrict__ a_src,
                                               float* __restrict__ a_dst) {
  int t = blockIdx.x*256 + threadIdx.x;
  if (t >= NN*HEADS) return;
  int n = t >> 2, h = t & 3;
  const unsigned short* base = xpb + (size_t)n*HC + h*HID;
  float s = 0.f, d = 0.f;
  #pragma unroll
  for (int j = 0; j < HID; ++j) {
    float v = bf2f(base[j]);
    s = fmaf(v, as_[h*HID + j], s);
    d = fmaf(v, ad_[h*HID + j], d);
  }
  a_src[t] = s; a_dst[t] = d;
}

// fused layer-2 aggregate + skip + classifier
__global__ void __launch_bounds__(128) k_final(const int* __restrict__ row_start, const int2* __restrict__ adj,
                                               const unsigned short* __restrict__ xpb, const float* __restrict__ ew,
                                               const float* __restrict__ g2b, const float* __restrict__ x,
                                               const float* __restrict__ skw, const float* __restrict__ skb,
                                               const float* __restrict__ clw, const float* __restrict__ clb,
                                               float* __restrict__ out) {
  __shared__ float sx[F_IN];
  __shared__ float red[2][NCLS];
  int n = blockIdx.x;
  int c = threadIdx.x, h = c >> 5;
  if (c < F_IN) sx[c] = x[(size_t)n*F_IN + c];
  __syncthreads();
  int beg = row_start[n], end = row_start[n + 1];
  float acc = 0.f, ssum = 0.f;
  int i = beg;
  for (; i + 3 < end; i += 4) {
    int s0 = adj[i].x, s1 = adj[i+1].x, s2 = adj[i+2].x, s3 = adj[i+3].x;
    float w0 = ew[(size_t)i*4 + h], w1 = ew[(size_t)(i+1)*4 + h];
    float w2 = ew[(size_t)(i+2)*4 + h], w3 = ew[(size_t)(i+3)*4 + h];
    float x0 = bf2f(xpb[(size_t)s0*HC + c]), x1 = bf2f(xpb[(size_t)s1*HC + c]);
    float x2 = bf2f(xpb[(size_t)s2*HC + c]), x3 = bf2f(xpb[(size_t)s3*HC + c]);
    ssum += (w0 + w1) + (w2 + w3);
    acc = fmaf(w0, x0, fmaf(w1, x1, fmaf(w2, x2, fmaf(w3, x3, acc))));
  }
  for (; i < end; ++i) {
    int s0 = adj[i].x;
    float w0 = ew[(size_t)i*4 + h];
    ssum += w0;
    acc = fmaf(w0, bf2f(xpb[(size_t)s0*HC + c]), acc);
  }
  float val = elu_f(acc / (ssum + 1e-16f) + g2b[c]);
  float skipv = skb[c];
  #pragma unroll
  for (int k = 0; k < F_IN; ++k) skipv = fmaf(sx[k], skw[c*F_IN + k], skipv);
  float r = val + skipv;
  float p0 = r*clw[0*HC + c], p1 = r*clw[1*HC + c], p2 = r*clw[2*HC + c];
  float p3 = r*clw[3*HC + c], p4 = r*clw[4*HC + c];
  #pragma unroll
  for (int m = 32; m; m >>= 1) {
    p0 += __shfl_xor(p0, m); p1 += __shfl_xor(p1, m); p2 += __shfl_xor(p2, m);
    p3 += __shfl_xor(p3, m); p4 += __shfl_xor(p4, m);
  }
  int wave = c >> 6;
  if ((c & 63) == 0) {
    red[wave][0] = p0; red[wave][1] = p1; red[wave][2] = p2; red[wave][3] = p3; red[wave][4] = p4;
  }
  __syncthreads();
  if (c < NCLS) out[(size_t)n*NCLS + c] = red[0][c] + red[1][c] + clb[c];
}

extern "C" void kernel_launch(void* const* d_in, const int* in_sizes, int n_in,
                              void* d_out, int out_size, void* d_ws, size_t ws_size,
                              hipStream_t stream) {
  const float* x      = (const float*)d_in[0];
  const int*   ei     = (const int*)d_in[1];
  const float* eattr  = (const float*)d_in[2];
  const float* ee_w1  = (const float*)d_in[3];
  const float* ee_b1  = (const float*)d_in[4];
  const float* ee_w2  = (const float*)d_in[5];
  const float* ee_b2  = (const float*)d_in[6];
  const float* g1_W   = (const float*)d_in[7];
  const float* g1_We  = (const float*)d_in[8];
  const float* g1_as  = (const float*)d_in[9];
  const float* g1_ad  = (const float*)d_in[10];
  const float* g1_ae  = (const float*)d_in[11];
  const float* g1_b   = (const float*)d_in[12];
  const float* g2_W   = (const float*)d_in[13];
  const float* g2_We  = (const float*)d_in[14];
  const float* g2_as  = (const float*)d_in[15];
  const float* g2_ad  = (const float*)d_in[16];
  const float* g2_ae  = (const float*)d_in[17];
  const float* g2_b   = (const float*)d_in[18];
  const float* skip_w = (const float*)d_in[19];
  const float* skip_b = (const float*)d_in[20];
  const float* cls_w  = (const float*)d_in[21];
  const float* cls_b  = (const float*)d_in[22];
  float* out = (float*)d_out;
  (void)in_sizes; (void)n_in; (void)out_size; (void)ws_size;

  char* ws = (char*)d_ws;
  size_t off = 0;
  auto alloc = [&](size_t bytes) -> void* {
    void* p = ws + off;
    off = (off + bytes + 255) & ~(size_t)255;
    return p;
  };
  float* ve          = (float*)alloc(32*4);
  int* counts        = (int*)alloc((size_t)NN*4);
  int* row_start     = (int*)alloc((size_t)(NN + 1)*4);
  int* cursor        = (int*)alloc((size_t)NN*4);
  int* bexcl         = (int*)alloc(256*4);
  int* bsum          = (int*)alloc(256*4);
  float4* a_e1       = (float4*)alloc((size_t)EE*16);   // reused as h1b after escore1
  float4* a_e2       = (float4*)alloc((size_t)EE*16);
  int2* adj          = (int2*)alloc((size_t)EE*8);
  int* dstp          = (int*)alloc((size_t)EE*4);
  float* ew          = (float*)alloc((size_t)EE*HEADS*4);  // reused for both layers
  unsigned short* xpb = (unsigned short*)alloc((size_t)NN*HC*2);  // reused for both layers
  unsigned short* w2b = (unsigned short*)alloc((size_t)HC*HC*2);
  float* a_src       = (float*)alloc((size_t)NN*HEADS*4);  // reused layer-2
  float* a_dst       = (float*)alloc((size_t)NN*HEADS*4);
  unsigned short* h1b = (unsigned short*)a_e1;  // alias: a_e1 dead after escore1 (12.8 MB each)

  hipMemsetAsync(counts, 0, (size_t)NN*4, stream);
  k_prep_ve<<<1, 32, 0, stream>>>(g1_We, g1_ae, g2_We, g2_ae, ve);
  k_edge_enc<<<EE/256, 256, 0, stream>>>(eattr, ee_w1, ee_b1, ee_w2, ee_b2, ve, a_e1, a_e2);
  k_hist<<<EE/256, 256, 0, stream>>>(ei, counts);
  k_scan_block<<<SCAN_BLOCKS, 256, 0, stream>>>(counts, bsum);
  k_scan_top<<<1, 256, 0, stream>>>(bsum, bexcl, row_start);
  k_scan_final<<<SCAN_BLOCKS, 256, 0, stream>>>(counts, bexcl, row_start, cursor);
  k_scatter<<<EE/256, 256, 0, stream>>>(ei, cursor, adj);
  k_expand_dst<<<SCAN_BLOCKS, 256, 0, stream>>>(row_start, dstp);
  k_node1<<<2048, 128, 0, stream>>>(x, g1_W, g1_as, g1_ad, xpb, a_src, a_dst);
  k_escore<<<(EE*HEADS)/256, 256, 0, stream>>>(adj, dstp, a_src, a_dst, (const float*)a_e1, ew);
  k_agg1<<<NN, 128, 0, stream>>>(row_start, adj, xpb, ew, g1_b, h1b);
  k_tobf16<<<(HC*HC)/256, 256, 0, stream>>>(g2_W, w2b, HC*HC);
  k_xp2<<<(NN/16 + 3)/4, 256, 0, stream>>>(h1b, w2b, xpb);
  k_coef2<<<(NN*HEADS + 255)/256, 256, 0, stream>>>(xpb, g2_as, g2_ad, a_src, a_dst);
  k_escore<<<(EE*HEADS)/256, 256, 0, stream>>>(adj, dstp, a_src, a_dst, (const float*)a_e2, ew);
  k_final<<<NN, 128, 0, stream>>>(row_start, adj, xpb, ew, g2_b, x, skip_w, skip_b, cls_w, cls_b, out);
}

// Round 3
// 427.415 us; speedup vs baseline: 1.4732x; 1.1032x over previous
//
#include <hip/hip_runtime.h>
#include <hip/hip_bf16.h>
#include <math.h>

#define NN 50000
#define EE 800000
#define F_IN 16
#define HID 32
#define HEADS 4
#define HC 128
#define NCLS 5
#define EF 8
#define NEG_SLOPE 0.2f
#define SCAN_BLOCKS 196  // ceil(50000/256)

typedef __attribute__((ext_vector_type(8))) short short8;
typedef __attribute__((ext_vector_type(4))) float floatx4;

__device__ __forceinline__ float lrelu_f(float v) { return v > 0.f ? v : NEG_SLOPE * v; }
__device__ __forceinline__ float elu_f(float v) { return v > 0.f ? v : expm1f(v); }
__device__ __forceinline__ unsigned short f2bf(float v) {
  __hip_bfloat16 b = __float2bfloat16(v);
  unsigned short u; __builtin_memcpy(&u, &b, 2); return u;
}
__device__ __forceinline__ float bf2f(unsigned short u) {
  unsigned v = (unsigned)u << 16; float f; __builtin_memcpy(&f, &v, 4); return f;
}
// unpack 2 bf16 (packed in ushort2) -> 2 floats with 2 VALU ops
__device__ __forceinline__ void unpack2(ushort2 v, float& lo, float& hi) {
  unsigned u; __builtin_memcpy(&u, &v, 4);
  unsigned a = u << 16, b = u & 0xffff0000u;
  __builtin_memcpy(&lo, &a, 4); __builtin_memcpy(&hi, &b, 4);
}

// edge encoder + ve precompute + degree histogram, all fused.
// ea = relu(attr@w1^T+b1)@w2^T+b2 ; a_e_l = ea @ ve_l -> float4/edge/layer
__global__ void __launch_bounds__(256) k_edge_enc(
    const float* __restrict__ eattr, const float* __restrict__ w1, const float* __restrict__ b1,
    const float* __restrict__ w2, const float* __restrict__ b2,
    const float* __restrict__ We1, const float* __restrict__ ae1,
    const float* __restrict__ We2, const float* __restrict__ ae2,
    const int* __restrict__ ei, int* __restrict__ counts,
    float4* __restrict__ a_e1, float4* __restrict__ a_e2) {
  __shared__ float sw1[HID*EF], sb1[HID], sw2[HEADS*HID], sb2[HEADS], sve[32];
  int tid = threadIdx.x;
  sw1[tid] = w1[tid];
  if (tid < HID) sb1[tid] = b1[tid];
  if (tid < HEADS*HID) sw2[tid] = w2[tid];
  if (tid < HEADS) sb2[tid] = b2[tid];
  if (tid < 32) {  // ve[layer*16 + k*4 + h] = sum_c We[(h*32+c)*4+k] * ae[h*32+c]
    int layer = tid >> 4, idx = tid & 15, k = idx >> 2, h = idx & 3;
    const float* We = layer ? We2 : We1;
    const float* ae = layer ? ae2 : ae1;
    float s = 0.f;
    for (int c = 0; c < HID; ++c) s += We[(h*HID + c)*HEADS + k] * ae[h*HID + c];
    sve[layer*16 + k*4 + h] = s;
  }
  __syncthreads();
  int e = blockIdx.x*256 + tid;
  if (e >= EE) return;
  atomicAdd(&counts[ei[EE + e]], 1);   // fused degree histogram
  const float4* ap = (const float4*)(eattr + (size_t)e*EF);
  float4 A0 = ap[0], A1 = ap[1];
  float ea0=A0.x, ea1=A0.y, ea2=A0.z, ea3=A0.w, ea4=A1.x, ea5=A1.y, ea6=A1.z, ea7=A1.w;
  float enc0=sb2[0], enc1=sb2[1], enc2=sb2[2], enc3=sb2[3];
  #pragma unroll
  for (int j = 0; j < HID; ++j) {
    float hsum = sb1[j];
    hsum = fmaf(ea0, sw1[j*EF+0], hsum); hsum = fmaf(ea1, sw1[j*EF+1], hsum);
    hsum = fmaf(ea2, sw1[j*EF+2], hsum); hsum = fmaf(ea3, sw1[j*EF+3], hsum);
    hsum = fmaf(ea4, sw1[j*EF+4], hsum); hsum = fmaf(ea5, sw1[j*EF+5], hsum);
    hsum = fmaf(ea6, sw1[j*EF+6], hsum); hsum = fmaf(ea7, sw1[j*EF+7], hsum);
    hsum = fmaxf(hsum, 0.f);
    enc0 = fmaf(hsum, sw2[0*HID+j], enc0);
    enc1 = fmaf(hsum, sw2[1*HID+j], enc1);
    enc2 = fmaf(hsum, sw2[2*HID+j], enc2);
    enc3 = fmaf(hsum, sw2[3*HID+j], enc3);
  }
  float4 r1, r2;
  r1.x = enc0*sve[0]  + enc1*sve[4]  + enc2*sve[8]   + enc3*sve[12];
  r1.y = enc0*sve[1]  + enc1*sve[5]  + enc2*sve[9]   + enc3*sve[13];
  r1.z = enc0*sve[2]  + enc1*sve[6]  + enc2*sve[10]  + enc3*sve[14];
  r1.w = enc0*sve[3]  + enc1*sve[7]  + enc2*sve[11]  + enc3*sve[15];
  r2.x = enc0*sve[16] + enc1*sve[20] + enc2*sve[24]  + enc3*sve[28];
  r2.y = enc0*sve[17] + enc1*sve[21] + enc2*sve[25]  + enc3*sve[29];
  r2.z = enc0*sve[18] + enc1*sve[22] + enc2*sve[26]  + enc3*sve[30];
  r2.w = enc0*sve[19] + enc1*sve[23] + enc2*sve[27]  + enc3*sve[31];
  a_e1[e] = r1; a_e2[e] = r2;
}

__global__ void __launch_bounds__(256) k_scan_block(const int* __restrict__ counts, int* __restrict__ bsum) {
  __shared__ int s[256];
  int tid = threadIdx.x;
  int idx = blockIdx.x*256 + tid;
  s[tid] = (idx < NN) ? counts[idx] : 0;
  for (int o = 128; o; o >>= 1) { __syncthreads(); if (tid < o) s[tid] += s[tid + o]; }
  if (tid == 0) bsum[blockIdx.x] = s[0];
}

__global__ void __launch_bounds__(256) k_scan_top(const int* __restrict__ bsum, int* __restrict__ bexcl,
                                                  int* __restrict__ row_start) {
  __shared__ int s[256];
  int tid = threadIdx.x;
  int v = (tid < SCAN_BLOCKS) ? bsum[tid] : 0;
  s[tid] = v; __syncthreads();
  for (int o = 1; o < 256; o <<= 1) {
    int t2 = (tid >= o) ? s[tid - o] : 0;
    __syncthreads();
    s[tid] += t2;
    __syncthreads();
  }
  if (tid < SCAN_BLOCKS) bexcl[tid] = s[tid] - v;
  if (tid == 0) row_start[NN] = EE;
}

// scan finalize + dstp expansion fused
__global__ void __launch_bounds__(256) k_scan_final(const int* __restrict__ counts, const int* __restrict__ bexcl,
                                                    int* __restrict__ row_start, int* __restrict__ cursor,
                                                    int* __restrict__ dstp) {
  __shared__ int s[256];
  int tid = threadIdx.x;
  int idx = blockIdx.x*256 + tid;
  int v = (idx < NN) ? counts[idx] : 0;
  s[tid] = v; __syncthreads();
  for (int o = 1; o < 256; o <<= 1) {
    int t2 = (tid >= o) ? s[tid - o] : 0;
    __syncthreads();
    s[tid] += t2;
    __syncthreads();
  }
  int excl = s[tid] - v + bexcl[blockIdx.x];
  if (idx < NN) {
    row_start[idx] = excl; cursor[idx] = excl;
    for (int i = excl; i < excl + v; ++i) dstp[i] = idx;
  }
}

__global__ void __launch_bounds__(256) k_scatter(const int* __restrict__ ei, int* __restrict__ cursor,
                                                 int2* __restrict__ adj, int* __restrict__ srcp) {
  int e = blockIdx.x*256 + threadIdx.x;
  if (e >= EE) return;
  int src = ei[e], dst = ei[EE + e];
  int pos = atomicAdd(&cursor[dst], 1);
  adj[pos] = make_int2(src, e);
  srcp[pos] = src;
}

// layer-1 node phase: xpb = bf16(x @ W^T), a_src/a_dst per (node,head)
__global__ void __launch_bounds__(128) k_node1(const float* __restrict__ x, const float* __restrict__ W,
                                               const float* __restrict__ as_, const float* __restrict__ ad_,
                                               unsigned short* __restrict__ xpb, float* __restrict__ a_src,
                                               float* __restrict__ a_dst) {
  __shared__ float sW[HC*17];
  __shared__ float sas[HC], sad[HC];
  __shared__ float sx[F_IN];
  int tid = threadIdx.x;
  for (int i = tid; i < HC*F_IN; i += 128) { int r = i >> 4, k = i & 15; sW[r*17 + k] = W[i]; }
  sas[tid] = as_[tid]; sad[tid] = ad_[tid];
  int h = tid >> 5;
  for (int n = blockIdx.x; n < NN; n += gridDim.x) {
    __syncthreads();
    if (tid < F_IN) sx[tid] = x[(size_t)n*F_IN + tid];
    __syncthreads();
    float xv = 0.f;
    #pragma unroll
    for (int k = 0; k < F_IN; ++k) xv = fmaf(sx[k], sW[tid*17 + k], xv);
    xpb[(size_t)n*HC + tid] = f2bf(xv);
    float vs = xv * sas[tid], vd = xv * sad[tid];
    #pragma unroll
    for (int m = 16; m; m >>= 1) { vs += __shfl_xor(vs, m); vd += __shfl_xor(vd, m); }
    if ((tid & 31) == 0) { a_src[n*HEADS + h] = vs; a_dst[n*HEADS + h] = vd; }
  }
}

// per-edge exp weights: ew[pos*4+h] = exp(lrelu(a_src[src]+a_dst[dst]+a_e[eid]))
__global__ void __launch_bounds__(256) k_escore(const int2* __restrict__ adj, const int* __restrict__ dstp,
                                                const float* __restrict__ a_src, const float* __restrict__ a_dst,
                                                const float* __restrict__ a_e, float* __restrict__ ew) {
  int t = blockIdx.x*256 + threadIdx.x;
  if (t >= EE*HEADS) return;
  int pos = t >> 2, h = t & 3;
  int2 se = adj[pos];
  int dst = dstp[pos];
  float v = a_src[se.x*HEADS + h] + a_dst[dst*HEADS + h] + a_e[(size_t)se.y*HEADS + h];
  ew[t] = __expf(lrelu_f(v));
}

// wave-per-node layer-1 aggregate: softmax-normalize + bias + elu -> h1 (bf16)
// lane handles channels (2*lane, 2*lane+1); src broadcast via readlane -> SGPR gather base
__global__ void __launch_bounds__(256) k_agg1(const int* __restrict__ row_start, const int* __restrict__ srcp,
                                              const unsigned short* __restrict__ xpb, const float* __restrict__ ew,
                                              const float* __restrict__ bias, unsigned short* __restrict__ h1b) {
  int wv = threadIdx.x >> 6, lane = threadIdx.x & 63;
  int n = blockIdx.x*4 + wv;
  if (n >= NN) return;
  int h = lane >> 4, c2 = lane*2;
  int beg = row_start[n], end = row_start[n+1];
  const ushort2* xp2 = (const ushort2*)xpb;
  float acc0 = 0.f, acc1 = 0.f, ssum = 0.f;
  for (int cb = beg; cb < end; cb += 64) {
    int navail = end - cb;
    int cnt = navail < 64 ? navail : 64;
    int sv = srcp[cb + (lane < navail ? lane : navail - 1)];
    int j = 0;
    for (; j + 3 < cnt; j += 4) {
      int s0 = __builtin_amdgcn_readlane(sv, j);
      int s1 = __builtin_amdgcn_readlane(sv, j+1);
      int s2 = __builtin_amdgcn_readlane(sv, j+2);
      int s3 = __builtin_amdgcn_readlane(sv, j+3);
      ushort2 v0 = xp2[(size_t)s0*64 + lane];
      ushort2 v1 = xp2[(size_t)s1*64 + lane];
      ushort2 v2 = xp2[(size_t)s2*64 + lane];
      ushort2 v3 = xp2[(size_t)s3*64 + lane];
      float w0 = ew[(size_t)(cb+j)*4 + h],   w1 = ew[(size_t)(cb+j+1)*4 + h];
      float w2 = ew[(size_t)(cb+j+2)*4 + h], w3 = ew[(size_t)(cb+j+3)*4 + h];
      float a0, b0, a1, b1, a2, b2, a3, b3;
      unpack2(v0, a0, b0); unpack2(v1, a1, b1); unpack2(v2, a2, b2); unpack2(v3, a3, b3);
      ssum += (w0 + w1) + (w2 + w3);
      acc0 = fmaf(w0, a0, fmaf(w1, a1, fmaf(w2, a2, fmaf(w3, a3, acc0))));
      acc1 = fmaf(w0, b0, fmaf(w1, b1, fmaf(w2, b2, fmaf(w3, b3, acc1))));
    }
    for (; j < cnt; ++j) {
      int s0 = __builtin_amdgcn_readlane(sv, j);
      ushort2 v0 = xp2[(size_t)s0*64 + lane];
      float w0 = ew[(size_t)(cb+j)*4 + h];
      float a0, b0; unpack2(v0, a0, b0);
      ssum += w0;
      acc0 = fmaf(w0, a0, acc0); acc1 = fmaf(w0, b0, acc1);
    }
  }
  float inv = 1.f / (ssum + 1e-16f);
  ushort2 o;
  o.x = f2bf(elu_f(acc0*inv + bias[c2]));
  o.y = f2bf(elu_f(acc1*inv + bias[c2+1]));
  ((ushort2*)h1b)[(size_t)n*64 + lane] = o;
}

__global__ void __launch_bounds__(256) k_tobf16(const float* __restrict__ in, unsigned short* __restrict__ out, int n) {
  int i = blockIdx.x*256 + threadIdx.x;
  if (i < n) out[i] = f2bf(in[i]);
}

// layer-2 node GEMM: xp2 = h1b @ W2^T via 16x16x32 bf16 MFMA, write bf16
__global__ void __launch_bounds__(256) k_xp2(const unsigned short* __restrict__ h1b,
                                             const unsigned short* __restrict__ w2b,
                                             unsigned short* __restrict__ xpb) {
  int wave = threadIdx.x >> 6;
  int lane = threadIdx.x & 63;
  int m0 = (blockIdx.x*4 + wave)*16;
  if (m0 >= NN) return;
  int ln = lane & 15;
  int quad = lane >> 4;
  const short8* arow = (const short8*)(h1b + (size_t)(m0 + ln)*HC) + quad;
  short8 a[4];
  #pragma unroll
  for (int kc = 0; kc < 4; ++kc) a[kc] = arow[kc*4];
  #pragma unroll
  for (int n0 = 0; n0 < 8; ++n0) {
    const short8* brow = (const short8*)(w2b + (size_t)(n0*16 + ln)*HC) + quad;
    floatx4 acc = {0.f, 0.f, 0.f, 0.f};
    #pragma unroll
    for (int kc = 0; kc < 4; ++kc) {
      short8 b = brow[kc*4];
      acc = __builtin_amdgcn_mfma_f32_16x16x32_bf16(a[kc], b, acc, 0, 0, 0);
    }
    #pragma unroll
    for (int r = 0; r < 4; ++r) {
      int mm = quad*4 + r;
      xpb[(size_t)(m0 + mm)*HC + n0*16 + ln] = f2bf(acc[r]);
    }
  }
}

// layer-2 attention coefficients from bf16 xp2
__global__ void __launch_bounds__(256) k_coef2(const unsigned short* __restrict__ xpb, const float* __restrict__ as_,
                                               const float* __restrict__ ad_, float* __restrict__ a_src,
                                               float* __restrict__ a_dst) {
  int t = blockIdx.x*256 + threadIdx.x;
  if (t >= NN*HEADS) return;
  int n = t >> 2, h = t & 3;
  const unsigned short* base = xpb + (size_t)n*HC + h*HID;
  float s = 0.f, d = 0.f;
  #pragma unroll
  for (int j = 0; j < HID; ++j) {
    float v = bf2f(base[j]);
    s = fmaf(v, as_[h*HID + j], s);
    d = fmaf(v, ad_[h*HID + j], d);
  }
  a_src[t] = s; a_dst[t] = d;
}

// wave-per-node layer-2 aggregate + skip + classifier
__global__ void __launch_bounds__(256) k_final(const int* __restrict__ row_start, const int* __restrict__ srcp,
                                               const unsigned short* __restrict__ xpb, const float* __restrict__ ew,
                                               const float* __restrict__ g2b, const float* __restrict__ x,
                                               const float* __restrict__ skw, const float* __restrict__ skb,
                                               const float* __restrict__ clw, const float* __restrict__ clb,
                                               float* __restrict__ out) {
  int wv = threadIdx.x >> 6, lane = threadIdx.x & 63;
  int n = blockIdx.x*4 + wv;
  if (n >= NN) return;
  int h = lane >> 4, c2 = lane*2;
  int beg = row_start[n], end = row_start[n+1];
  const ushort2* xp2 = (const ushort2*)xpb;
  float acc0 = 0.f, acc1 = 0.f, ssum = 0.f;
  for (int cb = beg; cb < end; cb += 64) {
    int navail = end - cb;
    int cnt = navail < 64 ? navail : 64;
    int sv = srcp[cb + (lane < navail ? lane : navail - 1)];
    int j = 0;
    for (; j + 3 < cnt; j += 4) {
      int s0 = __builtin_amdgcn_readlane(sv, j);
      int s1 = __builtin_amdgcn_readlane(sv, j+1);
      int s2 = __builtin_amdgcn_readlane(sv, j+2);
      int s3 = __builtin_amdgcn_readlane(sv, j+3);
      ushort2 v0 = xp2[(size_t)s0*64 + lane];
      ushort2 v1 = xp2[(size_t)s1*64 + lane];
      ushort2 v2 = xp2[(size_t)s2*64 + lane];
      ushort2 v3 = xp2[(size_t)s3*64 + lane];
      float w0 = ew[(size_t)(cb+j)*4 + h],   w1 = ew[(size_t)(cb+j+1)*4 + h];
      float w2 = ew[(size_t)(cb+j+2)*4 + h], w3 = ew[(size_t)(cb+j+3)*4 + h];
      float a0, b0, a1, b1, a2, b2, a3, b3;
      unpack2(v0, a0, b0); unpack2(v1, a1, b1); unpack2(v2, a2, b2); unpack2(v3, a3, b3);
      ssum += (w0 + w1) + (w2 + w3);
      acc0 = fmaf(w0, a0, fmaf(w1, a1, fmaf(w2, a2, fmaf(w3, a3, acc0))));
      acc1 = fmaf(w0, b0, fmaf(w1, b1, fmaf(w2, b2, fmaf(w3, b3, acc1))));
    }
    for (; j < cnt; ++j) {
      int s0 = __builtin_amdgcn_readlane(sv, j);
      ushort2 v0 = xp2[(size_t)s0*64 + lane];
      float w0 = ew[(size_t)(cb+j)*4 + h];
      float a0, b0; unpack2(v0, a0, b0);
      ssum += w0;
      acc0 = fmaf(w0, a0, acc0); acc1 = fmaf(w0, b0, acc1);
    }
  }
  float inv = 1.f / (ssum + 1e-16f);
  float v0 = elu_f(acc0*inv + g2b[c2]);
  float v1 = elu_f(acc1*inv + g2b[c2+1]);
  // skip: x row broadcast via shfl (lanes 0..15 hold x[k])
  float xv = x[(size_t)n*F_IN + (lane & 15)];
  float sk0 = skb[c2], sk1 = skb[c2+1];
  #pragma unroll
  for (int k = 0; k < F_IN; ++k) {
    float xk = __shfl(xv, k);
    sk0 = fmaf(xk, skw[c2*F_IN + k], sk0);
    sk1 = fmaf(xk, skw[(c2+1)*F_IN + k], sk1);
  }
  float r0 = v0 + sk0, r1 = v1 + sk1;
  #pragma unroll
  for (int k = 0; k < NCLS; ++k) {
    float p = fmaf(r0, clw[k*HC + c2], r1*clw[k*HC + c2 + 1]);
    #pragma unroll
    for (int m = 32; m; m >>= 1) p += __shfl_xor(p, m);
    if (lane == 0) out[(size_t)n*NCLS + k] = p + clb[k];
  }
}

extern "C" void kernel_launch(void* const* d_in, const int* in_sizes, int n_in,
                              void* d_out, int out_size, void* d_ws, size_t ws_size,
                              hipStream_t stream) {
  const float* x      = (const float*)d_in[0];
  const int*   ei     = (const int*)d_in[1];
  const float* eattr  = (const float*)d_in[2];
  const float* ee_w1  = (const float*)d_in[3];
  const float* ee_b1  = (const float*)d_in[4];
  const float* ee_w2  = (const float*)d_in[5];
  const float* ee_b2  = (const float*)d_in[6];
  const float* g1_W   = (const float*)d_in[7];
  const float* g1_We  = (const float*)d_in[8];
  const float* g1_as  = (const float*)d_in[9];
  const float* g1_ad  = (const float*)d_in[10];
  const float* g1_ae  = (const float*)d_in[11];
  const float* g1_b   = (const float*)d_in[12];
  const float* g2_W   = (const float*)d_in[13];
  const float* g2_We  = (const float*)d_in[14];
  const float* g2_as  = (const float*)d_in[15];
  const float* g2_ad  = (const float*)d_in[16];
  const float* g2_ae  = (const float*)d_in[17];
  const float* g2_b   = (const float*)d_in[18];
  const float* skip_w = (const float*)d_in[19];
  const float* skip_b = (const float*)d_in[20];
  const float* cls_w  = (const float*)d_in[21];
  const float* cls_b  = (const float*)d_in[22];
  float* out = (float*)d_out;
  (void)in_sizes; (void)n_in; (void)out_size; (void)ws_size;

  char* ws = (char*)d_ws;
  size_t off = 0;
  auto alloc = [&](size_t bytes) -> void* {
    void* p = ws + off;
    off = (off + bytes + 255) & ~(size_t)255;
    return p;
  };
  int* counts        = (int*)alloc((size_t)NN*4);
  int* row_start     = (int*)alloc((size_t)(NN + 1)*4);
  int* cursor        = (int*)alloc((size_t)NN*4);
  int* bexcl         = (int*)alloc(256*4);
  int* bsum          = (int*)alloc(256*4);
  float4* a_e1       = (float4*)alloc((size_t)EE*16);   // reused as h1b after escore1
  float4* a_e2       = (float4*)alloc((size_t)EE*16);
  int2* adj          = (int2*)alloc((size_t)EE*8);
  int* srcp          = (int*)alloc((size_t)EE*4);
  int* dstp          = (int*)alloc((size_t)EE*4);
  float* ew          = (float*)alloc((size_t)EE*HEADS*4);  // reused for both layers
  unsigned short* xpb = (unsigned short*)alloc((size_t)NN*HC*2);  // reused for both layers
  unsigned short* w2b = (unsigned short*)alloc((size_t)HC*HC*2);
  float* a_src       = (float*)alloc((size_t)NN*HEADS*4);  // reused layer-2
  float* a_dst       = (float*)alloc((size_t)NN*HEADS*4);
  unsigned short* h1b = (unsigned short*)a_e1;  // alias: a_e1 dead after escore1

  hipMemsetAsync(counts, 0, (size_t)NN*4, stream);
  k_edge_enc<<<EE/256, 256, 0, stream>>>(eattr, ee_w1, ee_b1, ee_w2, ee_b2,
                                         g1_We, g1_ae, g2_We, g2_ae, ei, counts, a_e1, a_e2);
  k_scan_block<<<SCAN_BLOCKS, 256, 0, stream>>>(counts, bsum);
  k_scan_top<<<1, 256, 0, stream>>>(bsum, bexcl, row_start);
  k_scan_final<<<SCAN_BLOCKS, 256, 0, stream>>>(counts, bexcl, row_start, cursor, dstp);
  k_scatter<<<EE/256, 256, 0, stream>>>(ei, cursor, adj, srcp);
  k_node1<<<2048, 128, 0, stream>>>(x, g1_W, g1_as, g1_ad, xpb, a_src, a_dst);
  k_escore<<<(EE*HEADS)/256, 256, 0, stream>>>(adj, dstp, a_src, a_dst, (const float*)a_e1, ew);
  k_agg1<<<(NN + 3)/4, 256, 0, stream>>>(row_start, srcp, xpb, ew, g1_b, h1b);
  k_tobf16<<<(HC*HC)/256, 256, 0, stream>>>(g2_W, w2b, HC*HC);
  k_xp2<<<(NN/16 + 3)/4, 256, 0, stream>>>(h1b, w2b, xpb);
  k_coef2<<<(NN*HEADS + 255)/256, 256, 0, stream>>>(xpb, g2_as, g2_ad, a_src, a_dst);
  k_escore<<<(EE*HEADS)/256, 256, 0, stream>>>(adj, dstp, a_src, a_dst, (const float*)a_e2, ew);
  k_final<<<(NN + 3)/4, 256, 0, stream>>>(row_start, srcp, xpb, ew, g2_b, x, skip_w, skip_b, cls_w, cls_b, out);
}